// Round 5
// baseline (235.849 us; speedup 1.0000x reference)
//
#include <hip/hip_runtime.h>

typedef unsigned short u16;
typedef __attribute__((ext_vector_type(8))) short short8;
typedef __attribute__((ext_vector_type(4))) short short4v;
typedef __attribute__((ext_vector_type(4))) float f32x4;
typedef __attribute__((ext_vector_type(16))) float f32x16;

#define MFMA16(a, b, c) __builtin_amdgcn_mfma_f32_16x16x32_bf16(a, b, c, 0, 0, 0)
#define MFMA32(a, b, c) __builtin_amdgcn_mfma_f32_32x32x16_bf16(a, b, c, 0, 0, 0)

#define BB 8
#define NN 1024
#define DD 1024
#define HH 16
#define HD 64
#define MM (BB * NN)
// 0.125 (hd^-0.5) * log2(e): softmax computed in exp2 domain
#define SCLOG2 0.18033688011112042f

static __device__ __forceinline__ u16 f2bf(float f) {
  unsigned u = __float_as_uint(f);
  u += 0x7fffu + ((u >> 16) & 1u);  // RNE
  return (u16)(u >> 16);
}

static __device__ __forceinline__ void gld16(const void* g, void* l) {
  __builtin_amdgcn_global_load_lds((const __attribute__((address_space(1))) void*)g,
                                   (__attribute__((address_space(3))) void*)l, 16, 0, 0);
}

static __device__ __forceinline__ unsigned cvtpk(float lo, float hi) {
  unsigned r;
  asm("v_cvt_pk_bf16_f32 %0, %1, %2" : "=v"(r) : "v"(lo), "v"(hi));
  return r;
}

static __device__ __forceinline__ f32x16 zero16() {
  f32x16 v;
#pragma unroll
  for (int i = 0; i < 16; ++i) v[i] = 0.f;
  return v;
}

// ---------------- lengths from mask (auto-detect bool-byte vs int32) --------
__global__ void lens_kernel(const unsigned char* __restrict__ mask, int* __restrict__ lens) {
  __shared__ int acc[BB];
  const int t = threadIdx.x;
  if (t < BB) acc[t] = 0;
  __syncthreads();
  const bool isbyte = (mask[1] != 0);  // lengths >= 512 so element 1 is true
  for (int b = 0; b < BB; ++b) {
    int s = 0;
    if (isbyte) {
      for (int i = t; i < NN; i += 256) s += mask[(size_t)b * NN + i] ? 1 : 0;
    } else {
      const int* mi = (const int*)mask;
      for (int i = t; i < NN; i += 256) s += mi[(size_t)b * NN + i] != 0 ? 1 : 0;
    }
    if (s) atomicAdd(&acc[b], s);
  }
  __syncthreads();
  if (t < BB) lens[t] = acc[t];
}

// ---------------- f32 -> bf16 cast (8 elems/thread) -------------------------
__global__ __launch_bounds__(256) void cast_bf16_kernel(const float* __restrict__ in,
                                                        u16* __restrict__ out, int n8) {
  const int i = blockIdx.x * 256 + threadIdx.x;
  if (i >= n8) return;
  const f32x4* p = (const f32x4*)in + (size_t)i * 2;
  const f32x4 a = p[0], b = p[1];
  short8 o;
  o[0] = (short)f2bf(a[0]); o[1] = (short)f2bf(a[1]);
  o[2] = (short)f2bf(a[2]); o[3] = (short)f2bf(a[3]);
  o[4] = (short)f2bf(b[0]); o[5] = (short)f2bf(b[1]);
  o[6] = (short)f2bf(b[2]); o[7] = (short)f2bf(b[3]);
  *(short8*)(out + (size_t)i * 8) = o;
}

// ---------------- fused cast of the 4 weight matrices -----------------------
__global__ __launch_bounds__(256) void cast4_bf16_kernel(const float* __restrict__ a, const float* __restrict__ b,
                                                         const float* __restrict__ c, const float* __restrict__ d,
                                                         u16* __restrict__ oa, u16* __restrict__ ob,
                                                         u16* __restrict__ oc, u16* __restrict__ od) {
  const int i = blockIdx.x * 256 + threadIdx.x;
  const float* in;
  u16* out;
  switch (blockIdx.y) {
    case 0: in = a; out = oa; break;
    case 1: in = b; out = ob; break;
    case 2: in = c; out = oc; break;
    default: in = d; out = od; break;
  }
  const f32x4* p = (const f32x4*)in + (size_t)i * 2;
  const f32x4 va = p[0], vb = p[1];
  short8 o;
  o[0] = (short)f2bf(va[0]); o[1] = (short)f2bf(va[1]);
  o[2] = (short)f2bf(va[2]); o[3] = (short)f2bf(va[3]);
  o[4] = (short)f2bf(vb[0]); o[5] = (short)f2bf(vb[1]);
  o[6] = (short)f2bf(vb[2]); o[7] = (short)f2bf(vb[3]);
  *(short8*)(out + (size_t)i * 8) = o;
}

// ============ shared GEMM core: 128x128 tile, BK=64, T2 XOR swizzle =========
// LDS tile: 128 rows x 64 u16 (128 B rows). Swizzle: byte ^= (row&7)<<4 —
// applied to BOTH the gld16 global source column and the ds_read address
// (involution; LDS dest stays linear per rule 21). Kills the 8/16-way
// fragment-read bank conflict. Two 16-MFMA sub-steps (ks=0,1) per K-step.
#define GEMM_CORE(A_, B_)                                                       \
  for (int k0 = 0; k0 < 1024; k0 += 64) {                                       \
    __syncthreads();                                                            \
    _Pragma("unroll") for (int p = 0; p < 4; ++p) {                             \
      const int off = (p * 256 + t) * 16;                                       \
      const int row = off >> 7;                                                 \
      const int colb = (off & 127) ^ ((row & 7) << 4);                          \
      gld16(A_ + (size_t)(m0 + row) * 1024 + k0 + (colb >> 1), As + off / 2);   \
      gld16(B_ + (size_t)(n0 + row) * 1024 + k0 + (colb >> 1), Bs + off / 2);   \
    }                                                                           \
    __syncthreads();                                                            \
    _Pragma("unroll") for (int ks = 0; ks < 2; ++ks) {                          \
      short8 af[4], bf[4];                                                      \
      _Pragma("unroll") for (int mi = 0; mi < 4; ++mi) {                        \
        const int row = wr * 64 + mi * 16 + li;                                 \
        const int byo = row * 128 + ((ks * 64 + lg * 16) ^ ((row & 7) << 4));   \
        af[mi] = *(const short8*)((const char*)As + byo);                       \
      }                                                                         \
      _Pragma("unroll") for (int ni = 0; ni < 4; ++ni) {                        \
        const int row = wc * 64 + ni * 16 + li;                                 \
        const int byo = row * 128 + ((ks * 64 + lg * 16) ^ ((row & 7) << 4));   \
        bf[ni] = *(const short8*)((const char*)Bs + byo);                       \
      }                                                                         \
      __builtin_amdgcn_s_setprio(1);                                            \
      _Pragma("unroll") for (int mi = 0; mi < 4; ++mi)                          \
        _Pragma("unroll") for (int ni = 0; ni < 4; ++ni)                        \
            acc[mi][ni] = MFMA16(af[mi], bf[ni], acc[mi][ni]);                  \
      __builtin_amdgcn_s_setprio(0);                                            \
    }                                                                           \
  }

// ---------------- fused QKV projection: C_m = xb @ W_m^T, m in {k,q,v} ------
// grid (MM/128, 24): blockIdx.y -> (mat = y>>3, n0 = (y&7)*128).
// Blocks whose 128 rows are all >= len are skipped: those K/Q/V rows are
// provably never read by attn (i-tiles skip at i0>=len; j-loads stay below
// ceil64(len) which lies in a block with m0 < len).
__global__ __launch_bounds__(256) void gemm_qkv(const u16* __restrict__ A,
                                                const u16* __restrict__ Wk3, const u16* __restrict__ Wq3,
                                                const u16* __restrict__ Wv3,
                                                u16* __restrict__ kb, u16* __restrict__ qb,
                                                u16* __restrict__ vtb, const int* __restrict__ lens) {
  const int m0 = blockIdx.x * 128;
  if ((m0 & 1023) >= lens[m0 >> 10]) return;  // dead rows
  __shared__ u16 As[128 * 64];
  __shared__ u16 Bs[128 * 64];
  const int mat = blockIdx.y >> 3;
  const int n0 = (blockIdx.y & 7) * 128;
  const u16* Bw = (mat == 0) ? Wk3 : (mat == 1) ? Wq3 : Wv3;
  const int t = threadIdx.x;
  const int lane = t & 63;
  const int w = t >> 6;
  const int wr = w >> 1, wc = w & 1;
  const int li = lane & 15, lg = lane >> 4;
  f32x4 acc[4][4] = {};

  GEMM_CORE(A, Bw)

  if (mat == 2) {  // V: transposed per-head store
#pragma unroll
    for (int mi = 0; mi < 4; ++mi) {
      const int row = m0 + wr * 64 + mi * 16 + lg * 4;  // (b, j)
      const int bb = row >> 10, jj = row & 1023;
#pragma unroll
      for (int ni = 0; ni < 4; ++ni) {
        const int col = n0 + wc * 64 + ni * 16 + li;  // (h, x)
        const int h = col >> 6, x = col & 63;
        short4v st;
#pragma unroll
        for (int r = 0; r < 4; ++r) st[r] = (short)f2bf(acc[mi][ni][r]);
        *(short4v*)(vtb + ((size_t)((bb * HH + h) * HD + x)) * NN + jj) = st;
      }
    }
  } else {
    u16* C = (mat == 0) ? kb : qb;
    const float scale = (mat == 0) ? SCLOG2 : 1.0f;
#pragma unroll
    for (int mi = 0; mi < 4; ++mi)
#pragma unroll
      for (int ni = 0; ni < 4; ++ni) {
        const int col = n0 + wc * 64 + ni * 16 + li;
        const int rowb = m0 + wr * 64 + mi * 16 + lg * 4;
#pragma unroll
        for (int r = 0; r < 4; ++r)
          C[(size_t)(rowb + r) * 1024 + col] = f2bf(acc[mi][ni][r] * scale);
      }
  }
}

// ---------------- output GEMM: out = attb @ Wo^T + bo, mask-zeroed ----------
__global__ __launch_bounds__(256) void gemm_out(const u16* __restrict__ A, const u16* __restrict__ Bw,
                                                float* __restrict__ C, const float* __restrict__ bias,
                                                const int* __restrict__ lens) {
  const int m0 = blockIdx.x * 128;
  const int n0 = blockIdx.y * 128;
  const int t = threadIdx.x;
  if ((m0 & 1023) >= lens[m0 >> 10]) {  // fully-masked tile: store zeros only
    const int r = t >> 1, ch = (t & 1) * 64;
    float* Crow = C + (size_t)(m0 + r) * 1024 + n0 + ch;
    const f32x4 z = {0.f, 0.f, 0.f, 0.f};
#pragma unroll
    for (int c = 0; c < 16; ++c) *(f32x4*)(Crow + c * 4) = z;
    return;
  }
  __shared__ u16 As[128 * 64];
  __shared__ u16 Bs[128 * 64];
  const int lane = t & 63;
  const int w = t >> 6;
  const int wr = w >> 1, wc = w & 1;
  const int li = lane & 15, lg = lane >> 4;
  f32x4 acc[4][4] = {};

  GEMM_CORE(A, Bw)

#pragma unroll
  for (int ni = 0; ni < 4; ++ni) {
    const int col = n0 + wc * 64 + ni * 16 + li;
    const float bv = bias[col];
#pragma unroll
    for (int mi = 0; mi < 4; ++mi) {
      const int rowb = m0 + wr * 64 + mi * 16 + lg * 4;
#pragma unroll
      for (int r = 0; r < 4; ++r) {
        const int row = rowb + r;
        const int bb = row >> 10, ii = row & 1023;
        const float v = (ii < lens[bb]) ? (acc[mi][ni][r] + bv) : 0.f;
        C[(size_t)row * 1024 + col] = v;
      }
    }
  }
}

// ---------------- flash attention, 4 waves/block, 32 i-rows/wave ------------
// No LDS, no barriers (Common-mistake #7 / m169: at S=1024 the per-(b,h)
// Q/V panels are L2-resident — staging was pure overhead). Each wave loads
// its Q/V MFMA fragments directly (16 B/lane, full 128 B cache lines used).
// XCD swizzle (T1) keeps a (b,h)'s 8 i-blocks on one XCD's L2.
// S^T = mfma32(A=Q-frag, B=K-frag): lane l holds col i = l&31,
// row j = (reg&3) + 8*(reg>>2) + 4*(l>>5). Scores in exp2 domain (K
// pre-scaled by 0.125*log2e).
__global__ __launch_bounds__(256) void attn_kernel(const u16* __restrict__ Kb, const u16* __restrict__ Qb,
                                                   const u16* __restrict__ Vtb, u16* __restrict__ attb,
                                                   const int* __restrict__ lens) {
  const int bid = blockIdx.x;
  const int work = (bid & 7) * 128 + (bid >> 3);  // bijective, 1024 = 8*128
  const int ic = work & 7, h = (work >> 3) & 15, b = work >> 7;
  const int len = lens[b];
  const int i0 = ic * 128;
  if (i0 >= len) return;  // fully-masked rows zeroed by final GEMM
  const int t = threadIdx.x;
  const int w = t >> 6, l = t & 63;
  const int l31 = l & 31, hi = l >> 5;
  const int i0w = i0 + w * 32;

  // K fragments (B operand): col i = l31, k(hd) = ks*16 + hi*8 + e
  short8 kf[4];
  {
    const u16* kp = Kb + ((size_t)(b * NN + i0w + l31)) * DD + h * HD + hi * 8;
#pragma unroll
    for (int ks = 0; ks < 4; ++ks) kf[ks] = *(const short8*)(kp + ks * 16);
  }
  const u16* qp = Qb + ((size_t)(b * NN) + l31) * DD + h * HD + hi * 8;
  const u16* vp = Vtb + ((size_t)((b * HH + h) * HD) + l31) * NN + hi * 8;

  f32x16 o0 = zero16(), o1 = zero16();
  float m_run = -3.0e38f, l_run = 0.f;
  const int nt = (len + 63) >> 6;

  for (int jt = 0; jt < nt; ++jt) {
    const int j0 = jt * 64;
    // Q fragments: rows j0 + p*32 + l31, hd cols ks*16 + hi*8
    short8 qf0[4], qf1[4];
#pragma unroll
    for (int ks = 0; ks < 4; ++ks) {
      qf0[ks] = *(const short8*)(qp + (size_t)j0 * DD + ks * 16);
      qf1[ks] = *(const short8*)(qp + (size_t)(j0 + 32) * DD + ks * 16);
    }
    f32x16 s0 = zero16(), s1 = zero16();
    __builtin_amdgcn_s_setprio(1);
#pragma unroll
    for (int ks = 0; ks < 4; ++ks) s0 = MFMA32(qf0[ks], kf[ks], s0);
#pragma unroll
    for (int ks = 0; ks < 4; ++ks) s1 = MFMA32(qf1[ks], kf[ks], s1);
    __builtin_amdgcn_s_setprio(0);

    // V fragments (independent of softmax — issue early): rows x = p*32+l31,
    // j cols j0 + kk*16 + hi*8
    short8 vf0[4], vf1[4];
#pragma unroll
    for (int kk = 0; kk < 4; ++kk) {
      vf0[kk] = *(const short8*)(vp + j0 + kk * 16);
      vf1[kk] = *(const short8*)(vp + (size_t)32 * NN + j0 + kk * 16);
    }

    if (j0 + 64 > len) {  // uniform; only possible on last tile
#pragma unroll
      for (int r = 0; r < 16; ++r) {
        const int jl = (r & 3) + 8 * (r >> 2) + 4 * hi;
        if (j0 + jl >= len) s0[r] = -3.0e38f;
        if (j0 + 32 + jl >= len) s1[r] = -3.0e38f;
      }
    }

    float pmax = s0[0];
#pragma unroll
    for (int r = 1; r < 16; ++r) pmax = fmaxf(pmax, s0[r]);
#pragma unroll
    for (int r = 0; r < 16; ++r) pmax = fmaxf(pmax, s1[r]);
    pmax = fmaxf(pmax, __shfl_xor(pmax, 32));

    // defer-max (T13): skip O-rescale while tile max within 11.5 (log2) of m_run
    if (!__all(pmax <= m_run + 11.5f)) {
      const float mnew = fmaxf(m_run, pmax);
      const float al = __builtin_amdgcn_exp2f(m_run - mnew);
      l_run *= al;
#pragma unroll
      for (int r = 0; r < 16; ++r) { o0[r] *= al; o1[r] *= al; }
      m_run = mnew;
    }

    float rs = 0.f;
#pragma unroll
    for (int r = 0; r < 16; ++r) { const float p = __builtin_amdgcn_exp2f(s0[r] - m_run); s0[r] = p; rs += p; }
#pragma unroll
    for (int r = 0; r < 16; ++r) { const float p = __builtin_amdgcn_exp2f(s1[r] - m_run); s1[r] = p; rs += p; }
    rs += __shfl_xor(rs, 32);
    l_run += rs;

    // P -> PV B-fragments: per 16-j chunk, 4 cvt_pk + 2 permlane32_swap (T12).
    // v_permlane32_swap_b32 vdst, vsrc: vdst_new = {vdst.lo, vsrc.lo},
    // vsrc_new = {vdst.hi, vsrc.hi}; vdst = low-j word, vsrc = +8 word.
    short8 pf[4];
#pragma unroll
    for (int jk = 0; jk < 4; ++jk) {
      const f32x16& ss = (jk < 2) ? s0 : s1;
      const int kk = jk & 1;
      unsigned W0 = cvtpk(ss[8 * kk + 0], ss[8 * kk + 1]);
      unsigned W1 = cvtpk(ss[8 * kk + 2], ss[8 * kk + 3]);
      unsigned W2 = cvtpk(ss[8 * kk + 4], ss[8 * kk + 5]);
      unsigned W3 = cvtpk(ss[8 * kk + 6], ss[8 * kk + 7]);
      asm("v_permlane32_swap_b32 %0, %1" : "+v"(W0), "+v"(W2));
      asm("v_permlane32_swap_b32 %0, %1" : "+v"(W1), "+v"(W3));
      union { unsigned u[4]; short8 s; } pu;
      pu.u[0] = W0; pu.u[1] = W1; pu.u[2] = W2; pu.u[3] = W3;
      pf[jk] = pu.s;
    }

    __builtin_amdgcn_s_setprio(1);
#pragma unroll
    for (int kkg = 0; kkg < 4; ++kkg) {
      o0 = MFMA32(vf0[kkg], pf[kkg], o0);
      o1 = MFMA32(vf1[kkg], pf[kkg], o1);
    }
    __builtin_amdgcn_s_setprio(0);
  }

  const float inv = 1.f / l_run;
  u16* op = attb + (size_t)(b * NN + i0w + l31) * DD + h * HD + hi * 4;
#pragma unroll
  for (int xs = 0; xs < 2; ++xs) {
    const f32x16& oo = xs ? o1 : o0;
#pragma unroll
    for (int q = 0; q < 4; ++q) {
      short4v st;
#pragma unroll
      for (int e = 0; e < 4; ++e) st[e] = (short)f2bf(oo[q * 4 + e] * inv);
      *(short4v*)(op + xs * 32 + q * 8) = st;
    }
  }
}

// ---------------------------------------------------------------------------
extern "C" void kernel_launch(void* const* d_in, const int* in_sizes, int n_in,
                              void* d_out, int out_size, void* d_ws, size_t ws_size,
                              hipStream_t stream) {
  const float* x = (const float*)d_in[0];
  const unsigned char* mask = (const unsigned char*)d_in[1];
  const float* Wk = (const float*)d_in[2];
  const float* Wq = (const float*)d_in[3];
  const float* Wv = (const float*)d_in[4];
  const float* Wo = (const float*)d_in[5];
  const float* bo = (const float*)d_in[6];
  float* out = (float*)d_out;

  char* ws = (char*)d_ws;
  size_t o = 0;
  int* lens = (int*)(ws + o); o += 256;
  u16* xb  = (u16*)(ws + o); o += (size_t)MM * DD * 2;
  u16* wkb = (u16*)(ws + o); o += (size_t)DD * DD * 2;
  u16* wqb = (u16*)(ws + o); o += (size_t)DD * DD * 2;
  u16* wvb = (u16*)(ws + o); o += (size_t)DD * DD * 2;
  u16* wob = (u16*)(ws + o); o += (size_t)DD * DD * 2;
  u16* kb  = (u16*)(ws + o); o += (size_t)MM * DD * 2;
  u16* qb  = (u16*)(ws + o); o += (size_t)MM * DD * 2;
  u16* vtb = (u16*)(ws + o); o += (size_t)MM * DD * 2;
  u16* attb = xb;  // alias: x only needed until projections finish

  lens_kernel<<<dim3(1), dim3(256), 0, stream>>>(mask, lens);

  const int xn8 = MM * DD / 8;
  cast_bf16_kernel<<<dim3(xn8 / 256), dim3(256), 0, stream>>>(x, xb, xn8);
  cast4_bf16_kernel<<<dim3(DD * DD / 8 / 256, 4), dim3(256), 0, stream>>>(
      Wk, Wq, Wv, Wo, wkb, wqb, wvb, wob);

  gemm_qkv<<<dim3(MM / 128, 24), dim3(256), 0, stream>>>(xb, wkb, wqb, wvb, kb, qb, vtb, lens);

  attn_kernel<<<dim3(1024), dim3(256), 0, stream>>>(kb, qb, vtb, attb, lens);

  gemm_out<<<dim3(MM / 128, DD / 128), dim3(256), 0, stream>>>(attb, wob, out, bo, lens);
}

// Round 6
// 186.362 us; speedup vs baseline: 1.2655x; 1.2655x over previous
//
#include <hip/hip_runtime.h>

typedef unsigned short u16;
typedef __attribute__((ext_vector_type(8))) short short8;
typedef __attribute__((ext_vector_type(4))) short short4v;
typedef __attribute__((ext_vector_type(4))) float f32x4;
typedef __attribute__((ext_vector_type(16))) float f32x16;

#define MFMA16(a, b, c) __builtin_amdgcn_mfma_f32_16x16x32_bf16(a, b, c, 0, 0, 0)
#define MFMA32(a, b, c) __builtin_amdgcn_mfma_f32_32x32x16_bf16(a, b, c, 0, 0, 0)

#define BB 8
#define NN 1024
#define DD 1024
#define HH 16
#define HD 64
#define MM (BB * NN)
// 0.125 (hd^-0.5) * log2(e): softmax computed in exp2 domain
#define SCLOG2 0.18033688011112042f

static __device__ __forceinline__ u16 f2bf(float f) {
  unsigned u = __float_as_uint(f);
  u += 0x7fffu + ((u >> 16) & 1u);  // RNE
  return (u16)(u >> 16);
}

static __device__ __forceinline__ void gld16(const void* g, void* l) {
  __builtin_amdgcn_global_load_lds((const __attribute__((address_space(1))) void*)g,
                                   (__attribute__((address_space(3))) void*)l, 16, 0, 0);
}

static __device__ __forceinline__ unsigned cvtpk(float lo, float hi) {
  unsigned r;
  asm("v_cvt_pk_bf16_f32 %0, %1, %2" : "=v"(r) : "v"(lo), "v"(hi));
  return r;
}

static __device__ __forceinline__ f32x16 zero16() {
  f32x16 v;
#pragma unroll
  for (int i = 0; i < 16; ++i) v[i] = 0.f;
  return v;
}

// ---------------- lengths from mask (auto-detect bool-byte vs int32) --------
__global__ void lens_kernel(const unsigned char* __restrict__ mask, int* __restrict__ lens) {
  __shared__ int acc[BB];
  const int t = threadIdx.x;
  if (t < BB) acc[t] = 0;
  __syncthreads();
  const bool isbyte = (mask[1] != 0);  // lengths >= 512 so element 1 is true
  for (int b = 0; b < BB; ++b) {
    int s = 0;
    if (isbyte) {
      for (int i = t; i < NN; i += 256) s += mask[(size_t)b * NN + i] ? 1 : 0;
    } else {
      const int* mi = (const int*)mask;
      for (int i = t; i < NN; i += 256) s += mi[(size_t)b * NN + i] != 0 ? 1 : 0;
    }
    if (s) atomicAdd(&acc[b], s);
  }
  __syncthreads();
  if (t < BB) lens[t] = acc[t];
}

// ---------------- f32 -> bf16 cast (8 elems/thread) -------------------------
__global__ __launch_bounds__(256) void cast_bf16_kernel(const float* __restrict__ in,
                                                        u16* __restrict__ out, int n8) {
  const int i = blockIdx.x * 256 + threadIdx.x;
  if (i >= n8) return;
  const f32x4* p = (const f32x4*)in + (size_t)i * 2;
  const f32x4 a = p[0], b = p[1];
  short8 o;
  o[0] = (short)f2bf(a[0]); o[1] = (short)f2bf(a[1]);
  o[2] = (short)f2bf(a[2]); o[3] = (short)f2bf(a[3]);
  o[4] = (short)f2bf(b[0]); o[5] = (short)f2bf(b[1]);
  o[6] = (short)f2bf(b[2]); o[7] = (short)f2bf(b[3]);
  *(short8*)(out + (size_t)i * 8) = o;
}

// ---------------- fused cast of the 4 weight matrices -----------------------
__global__ __launch_bounds__(256) void cast4_bf16_kernel(const float* __restrict__ a, const float* __restrict__ b,
                                                         const float* __restrict__ c, const float* __restrict__ d,
                                                         u16* __restrict__ oa, u16* __restrict__ ob,
                                                         u16* __restrict__ oc, u16* __restrict__ od) {
  const int i = blockIdx.x * 256 + threadIdx.x;
  const float* in;
  u16* out;
  switch (blockIdx.y) {
    case 0: in = a; out = oa; break;
    case 1: in = b; out = ob; break;
    case 2: in = c; out = oc; break;
    default: in = d; out = od; break;
  }
  const f32x4* p = (const f32x4*)in + (size_t)i * 2;
  const f32x4 va = p[0], vb = p[1];
  short8 o;
  o[0] = (short)f2bf(va[0]); o[1] = (short)f2bf(va[1]);
  o[2] = (short)f2bf(va[2]); o[3] = (short)f2bf(va[3]);
  o[4] = (short)f2bf(vb[0]); o[5] = (short)f2bf(vb[1]);
  o[6] = (short)f2bf(vb[2]); o[7] = (short)f2bf(vb[3]);
  *(short8*)(out + (size_t)i * 8) = o;
}

// ============ shared GEMM core: 128x128 tile, BK=64, T2 XOR swizzle =========
// LDS tile: 128 rows x 64 u16 (128 B rows). Swizzle: byte ^= (row&7)<<4 —
// applied to BOTH the gld16 global source column and the ds_read address
// (involution; LDS dest stays linear per rule 21). Kills the 8/16-way
// fragment-read bank conflict. Two 16-MFMA sub-steps (ks=0,1) per K-step.
#define GEMM_CORE(A_, B_)                                                       \
  for (int k0 = 0; k0 < 1024; k0 += 64) {                                       \
    __syncthreads();                                                            \
    _Pragma("unroll") for (int p = 0; p < 4; ++p) {                             \
      const int off = (p * 256 + t) * 16;                                       \
      const int row = off >> 7;                                                 \
      const int colb = (off & 127) ^ ((row & 7) << 4);                          \
      gld16(A_ + (size_t)(m0 + row) * 1024 + k0 + (colb >> 1), As + off / 2);   \
      gld16(B_ + (size_t)(n0 + row) * 1024 + k0 + (colb >> 1), Bs + off / 2);   \
    }                                                                           \
    __syncthreads();                                                            \
    _Pragma("unroll") for (int ks = 0; ks < 2; ++ks) {                          \
      short8 af[4], bf[4];                                                      \
      _Pragma("unroll") for (int mi = 0; mi < 4; ++mi) {                        \
        const int row = wr * 64 + mi * 16 + li;                                 \
        const int byo = row * 128 + ((ks * 64 + lg * 16) ^ ((row & 7) << 4));   \
        af[mi] = *(const short8*)((const char*)As + byo);                       \
      }                                                                         \
      _Pragma("unroll") for (int ni = 0; ni < 4; ++ni) {                        \
        const int row = wc * 64 + ni * 16 + li;                                 \
        const int byo = row * 128 + ((ks * 64 + lg * 16) ^ ((row & 7) << 4));   \
        bf[ni] = *(const short8*)((const char*)Bs + byo);                       \
      }                                                                         \
      __builtin_amdgcn_s_setprio(1);                                            \
      _Pragma("unroll") for (int mi = 0; mi < 4; ++mi)                          \
        _Pragma("unroll") for (int ni = 0; ni < 4; ++ni)                        \
            acc[mi][ni] = MFMA16(af[mi], bf[ni], acc[mi][ni]);                  \
      __builtin_amdgcn_s_setprio(0);                                            \
    }                                                                           \
  }

// ---------------- fused QKV projection: C_m = xb @ W_m^T, m in {k,q,v} ------
// grid (MM/128, 24): blockIdx.y -> (mat = y>>3, n0 = (y&7)*128).
// Blocks whose 128 rows are all >= len are skipped: those K/Q/V rows are
// provably never read by attn (i-tiles skip at i0>=len; j-loads stay below
// ceil64(len) which lies in a block with m0 < len).
__global__ __launch_bounds__(256) void gemm_qkv(const u16* __restrict__ A,
                                                const u16* __restrict__ Wk3, const u16* __restrict__ Wq3,
                                                const u16* __restrict__ Wv3,
                                                u16* __restrict__ kb, u16* __restrict__ qb,
                                                u16* __restrict__ vtb, const int* __restrict__ lens) {
  const int m0 = blockIdx.x * 128;
  if ((m0 & 1023) >= lens[m0 >> 10]) return;  // dead rows
  __shared__ u16 As[128 * 64];
  __shared__ u16 Bs[128 * 64];
  const int mat = blockIdx.y >> 3;
  const int n0 = (blockIdx.y & 7) * 128;
  const u16* Bw = (mat == 0) ? Wk3 : (mat == 1) ? Wq3 : Wv3;
  const int t = threadIdx.x;
  const int lane = t & 63;
  const int w = t >> 6;
  const int wr = w >> 1, wc = w & 1;
  const int li = lane & 15, lg = lane >> 4;
  f32x4 acc[4][4] = {};

  GEMM_CORE(A, Bw)

  if (mat == 2) {  // V: transposed per-head store
#pragma unroll
    for (int mi = 0; mi < 4; ++mi) {
      const int row = m0 + wr * 64 + mi * 16 + lg * 4;  // (b, j)
      const int bb = row >> 10, jj = row & 1023;
#pragma unroll
      for (int ni = 0; ni < 4; ++ni) {
        const int col = n0 + wc * 64 + ni * 16 + li;  // (h, x)
        const int h = col >> 6, x = col & 63;
        short4v st;
#pragma unroll
        for (int r = 0; r < 4; ++r) st[r] = (short)f2bf(acc[mi][ni][r]);
        *(short4v*)(vtb + ((size_t)((bb * HH + h) * HD + x)) * NN + jj) = st;
      }
    }
  } else {
    u16* C = (mat == 0) ? kb : qb;
    const float scale = (mat == 0) ? SCLOG2 : 1.0f;
#pragma unroll
    for (int mi = 0; mi < 4; ++mi)
#pragma unroll
      for (int ni = 0; ni < 4; ++ni) {
        const int col = n0 + wc * 64 + ni * 16 + li;
        const int rowb = m0 + wr * 64 + mi * 16 + lg * 4;
#pragma unroll
        for (int r = 0; r < 4; ++r)
          C[(size_t)(rowb + r) * 1024 + col] = f2bf(acc[mi][ni][r] * scale);
      }
  }
}

// ---------------- output GEMM: out = attb @ Wo^T + bo, mask-zeroed ----------
__global__ __launch_bounds__(256) void gemm_out(const u16* __restrict__ A, const u16* __restrict__ Bw,
                                                float* __restrict__ C, const float* __restrict__ bias,
                                                const int* __restrict__ lens) {
  const int m0 = blockIdx.x * 128;
  const int n0 = blockIdx.y * 128;
  const int t = threadIdx.x;
  if ((m0 & 1023) >= lens[m0 >> 10]) {  // fully-masked tile: store zeros only
    const int r = t >> 1, ch = (t & 1) * 64;
    float* Crow = C + (size_t)(m0 + r) * 1024 + n0 + ch;
    const f32x4 z = {0.f, 0.f, 0.f, 0.f};
#pragma unroll
    for (int c = 0; c < 16; ++c) *(f32x4*)(Crow + c * 4) = z;
    return;
  }
  __shared__ u16 As[128 * 64];
  __shared__ u16 Bs[128 * 64];
  const int lane = t & 63;
  const int w = t >> 6;
  const int wr = w >> 1, wc = w & 1;
  const int li = lane & 15, lg = lane >> 4;
  f32x4 acc[4][4] = {};

  GEMM_CORE(A, Bw)

#pragma unroll
  for (int ni = 0; ni < 4; ++ni) {
    const int col = n0 + wc * 64 + ni * 16 + li;
    const float bv = bias[col];
#pragma unroll
    for (int mi = 0; mi < 4; ++mi) {
      const int rowb = m0 + wr * 64 + mi * 16 + lg * 4;
#pragma unroll
      for (int r = 0; r < 4; ++r) {
        const int row = rowb + r;
        const int bb = row >> 10, ii = row & 1023;
        const float v = (ii < lens[bb]) ? (acc[mi][ni][r] + bv) : 0.f;
        C[(size_t)row * 1024 + col] = v;
      }
    }
  }
}

// ---------------- flash attention, 4 waves/block, 32 i-rows/wave ------------
// LDS double-buffered Q/V staging via global_load_lds (cross-tile async
// prefetch — R5 showed removing it serializes L2 latency: 61 -> 114 us).
// Load-balanced XCD swizzle: bid = [b(3)|hbit(1)|ic(3)|xcd(3)], so each XCD
// gets 2 heads x all 8 batches (identical len-mix -> balanced) and a (b,h)'s
// 8 i-blocks stay on one XCD's L2 (16 groups x 272 KB ~ 4.3 MB/XCD).
// S^T = mfma32(A=Q-frag, B=K-frag): lane l holds col i = l&31,
// row j = (reg&3) + 8*(reg>>2) + 4*(l>>5). Scores in exp2 domain (K
// pre-scaled by 0.125*log2e). Q/V tiles (64 j) in FRAGMENT-MAJOR LDS order
// (linear global_load_lds dest, conflict-free ds_read_b128).
__global__ __launch_bounds__(256) void attn_kernel(const u16* __restrict__ Kb, const u16* __restrict__ Qb,
                                                   const u16* __restrict__ Vtb, u16* __restrict__ attb,
                                                   const int* __restrict__ lens) {
  const int bid = blockIdx.x;
  const int b = bid >> 7;
  const int ic = (bid >> 3) & 7;
  const int h = ((bid & 7) << 1) | ((bid >> 6) & 1);
  const int len = lens[b];
  const int i0 = ic * 128;
  if (i0 >= len) return;  // fully-masked rows zeroed by final GEMM
  const int t = threadIdx.x;
  const int w = t >> 6, l = t & 63;
  const int l31 = l & 31, hi = l >> 5;
  const int i0w = i0 + w * 32;

  __shared__ u16 Qs[2][4096];  // 8KB per buffer
  __shared__ u16 Vs[2][4096];

  // K fragments (B operand): col i = l31, k(hd) = ks*16 + hi*8 + e
  short8 kf[4];
  {
    const u16* kp = Kb + ((size_t)(b * NN + i0w + l31)) * DD + h * HD + hi * 8;
#pragma unroll
    for (int ks = 0; ks < 4; ++ks) kf[ks] = *(const short8*)(kp + ks * 16);
  }

  const size_t qsrc = ((size_t)(b * NN) + l31) * DD + h * HD + w * 16 + hi * 8;
  const size_t vsrc = ((size_t)((b * HH + h) * HD + l31)) * NN + w * 16 + hi * 8;

  auto STAGE = [&](int buf, int j0) {
    u16* qd = &Qs[buf][0] + t * 8;
    u16* vd = &Vs[buf][0] + t * 8;
    gld16(Qb + qsrc + (size_t)j0 * DD, qd);
    gld16(Qb + qsrc + (size_t)(j0 + 32) * DD, qd + 2048);
    gld16(Vtb + vsrc + j0, vd);
    gld16(Vtb + vsrc + 32 * NN + j0, vd + 2048);
  };

  f32x16 o0 = zero16(), o1 = zero16();
  float m_run = -3.0e38f, l_run = 0.f;
  const int nt = (len + 63) >> 6;

  STAGE(0, 0);
  __syncthreads();
  for (int jt = 0; jt < nt; ++jt) {
    const int cur = jt & 1;
    const int j0 = jt * 64;
    if (jt + 1 < nt) STAGE(cur ^ 1, j0 + 64);  // async prefetch, drained at end barrier

    const u16* Qc = &Qs[cur][0];
    const u16* Vc = &Vs[cur][0];
    f32x16 s0 = zero16(), s1 = zero16();
    __builtin_amdgcn_s_setprio(1);
#pragma unroll
    for (int ks = 0; ks < 4; ++ks) {
      const short8 qf = *(const short8*)(Qc + (ks * 64 + l) * 8);
      s0 = MFMA32(qf, kf[ks], s0);
    }
#pragma unroll
    for (int ks = 0; ks < 4; ++ks) {
      const short8 qf = *(const short8*)(Qc + ((4 + ks) * 64 + l) * 8);
      s1 = MFMA32(qf, kf[ks], s1);
    }
    __builtin_amdgcn_s_setprio(0);

    if (j0 + 64 > len) {  // uniform; only possible on last tile
#pragma unroll
      for (int r = 0; r < 16; ++r) {
        const int jl = (r & 3) + 8 * (r >> 2) + 4 * hi;
        if (j0 + jl >= len) s0[r] = -3.0e38f;
        if (j0 + 32 + jl >= len) s1[r] = -3.0e38f;
      }
    }

    float pmax = s0[0];
#pragma unroll
    for (int r = 1; r < 16; ++r) pmax = fmaxf(pmax, s0[r]);
#pragma unroll
    for (int r = 0; r < 16; ++r) pmax = fmaxf(pmax, s1[r]);
    pmax = fmaxf(pmax, __shfl_xor(pmax, 32));

    // defer-max (T13): skip O-rescale while tile max within 11.5 (log2) of m_run
    if (!__all(pmax <= m_run + 11.5f)) {
      const float mnew = fmaxf(m_run, pmax);
      const float al = __builtin_amdgcn_exp2f(m_run - mnew);
      l_run *= al;
#pragma unroll
      for (int r = 0; r < 16; ++r) { o0[r] *= al; o1[r] *= al; }
      m_run = mnew;
    }

    float rs = 0.f;
#pragma unroll
    for (int r = 0; r < 16; ++r) { const float p = __builtin_amdgcn_exp2f(s0[r] - m_run); s0[r] = p; rs += p; }
#pragma unroll
    for (int r = 0; r < 16; ++r) { const float p = __builtin_amdgcn_exp2f(s1[r] - m_run); s1[r] = p; rs += p; }
    rs += __shfl_xor(rs, 32);
    l_run += rs;

    // P -> PV B-fragments: per 16-j chunk, 4 cvt_pk + 2 permlane32_swap (T12).
    // v_permlane32_swap_b32 vdst, vsrc: vdst_new = {vdst.lo, vsrc.lo},
    // vsrc_new = {vdst.hi, vsrc.hi}; vdst = low-j word, vsrc = +8 word.
    short8 pf[4];
#pragma unroll
    for (int jk = 0; jk < 4; ++jk) {
      const f32x16& ss = (jk < 2) ? s0 : s1;
      const int kk = jk & 1;
      unsigned W0 = cvtpk(ss[8 * kk + 0], ss[8 * kk + 1]);
      unsigned W1 = cvtpk(ss[8 * kk + 2], ss[8 * kk + 3]);
      unsigned W2 = cvtpk(ss[8 * kk + 4], ss[8 * kk + 5]);
      unsigned W3 = cvtpk(ss[8 * kk + 6], ss[8 * kk + 7]);
      asm("v_permlane32_swap_b32 %0, %1" : "+v"(W0), "+v"(W2));
      asm("v_permlane32_swap_b32 %0, %1" : "+v"(W1), "+v"(W3));
      union { unsigned u[4]; short8 s; } pu;
      pu.u[0] = W0; pu.u[1] = W1; pu.u[2] = W2; pu.u[3] = W3;
      pf[jk] = pu.s;
    }

    __builtin_amdgcn_s_setprio(1);
#pragma unroll
    for (int kkg = 0; kkg < 4; ++kkg) {
      const short8 vf = *(const short8*)(Vc + (kkg * 64 + l) * 8);
      o0 = MFMA32(vf, pf[kkg], o0);
    }
#pragma unroll
    for (int kkg = 0; kkg < 4; ++kkg) {
      const short8 vf = *(const short8*)(Vc + ((4 + kkg) * 64 + l) * 8);
      o1 = MFMA32(vf, pf[kkg], o1);
    }
    __builtin_amdgcn_s_setprio(0);
    __syncthreads();  // drains prefetch (vmcnt) + this tile's ds_reads (lgkm)
  }

  const float inv = 1.f / l_run;
  u16* op = attb + (size_t)(b * NN + i0w + l31) * DD + h * HD + hi * 4;
#pragma unroll
  for (int xs = 0; xs < 2; ++xs) {
    const f32x16& oo = xs ? o1 : o0;
#pragma unroll
    for (int q = 0; q < 4; ++q) {
      short4v st;
#pragma unroll
      for (int e = 0; e < 4; ++e) st[e] = (short)f2bf(oo[q * 4 + e] * inv);
      *(short4v*)(op + xs * 32 + q * 8) = st;
    }
  }
}

// ---------------------------------------------------------------------------
extern "C" void kernel_launch(void* const* d_in, const int* in_sizes, int n_in,
                              void* d_out, int out_size, void* d_ws, size_t ws_size,
                              hipStream_t stream) {
  const float* x = (const float*)d_in[0];
  const unsigned char* mask = (const unsigned char*)d_in[1];
  const float* Wk = (const float*)d_in[2];
  const float* Wq = (const float*)d_in[3];
  const float* Wv = (const float*)d_in[4];
  const float* Wo = (const float*)d_in[5];
  const float* bo = (const float*)d_in[6];
  float* out = (float*)d_out;

  char* ws = (char*)d_ws;
  size_t o = 0;
  int* lens = (int*)(ws + o); o += 256;
  u16* xb  = (u16*)(ws + o); o += (size_t)MM * DD * 2;
  u16* wkb = (u16*)(ws + o); o += (size_t)DD * DD * 2;
  u16* wqb = (u16*)(ws + o); o += (size_t)DD * DD * 2;
  u16* wvb = (u16*)(ws + o); o += (size_t)DD * DD * 2;
  u16* wob = (u16*)(ws + o); o += (size_t)DD * DD * 2;
  u16* kb  = (u16*)(ws + o); o += (size_t)MM * DD * 2;
  u16* qb  = (u16*)(ws + o); o += (size_t)MM * DD * 2;
  u16* vtb = (u16*)(ws + o); o += (size_t)MM * DD * 2;
  u16* attb = xb;  // alias: x only needed until projections finish

  lens_kernel<<<dim3(1), dim3(256), 0, stream>>>(mask, lens);

  const int xn8 = MM * DD / 8;
  cast_bf16_kernel<<<dim3(xn8 / 256), dim3(256), 0, stream>>>(x, xb, xn8);
  cast4_bf16_kernel<<<dim3(DD * DD / 8 / 256, 4), dim3(256), 0, stream>>>(
      Wk, Wq, Wv, Wo, wkb, wqb, wvb, wob);

  gemm_qkv<<<dim3(MM / 128, 24), dim3(256), 0, stream>>>(xb, wkb, wqb, wvb, kb, qb, vtb, lens);

  attn_kernel<<<dim3(1024), dim3(256), 0, stream>>>(kb, qb, vtb, attb, lens);

  gemm_out<<<dim3(MM / 128, DD / 128), dim3(256), 0, stream>>>(attb, wob, out, bo, lens);
}